// Round 28
// baseline (5949.859 us; speedup 1.0000x reference)
//
#include <hip/hip_runtime.h>
#include <hip/hip_bf16.h>
#include <math.h>

typedef unsigned int u32;
typedef unsigned short u16;
typedef __attribute__((ext_vector_type(8))) short bf16x8;
typedef __attribute__((ext_vector_type(4))) float f32x4;

// ---------- bf16 helpers ----------
__device__ __forceinline__ float bfbits(u32 hi) { union { u32 u; float f; } v; v.u = hi; return v.f; }
__device__ __forceinline__ float lo16(u32 p) { return bfbits(p << 16); }
__device__ __forceinline__ float hi16(u32 p) { return bfbits(p & 0xffff0000u); }
__device__ __forceinline__ float b2f(u16 x) { return bfbits(((u32)x) << 16); }
__device__ __forceinline__ u16 f2b(float f) {
    union { float f; u32 u; } v; v.f = f;
    u32 u = v.u;
    u32 r = (u + 0x7fffu + ((u >> 16) & 1u)) >> 16;  // RNE
    return (u16)r;
}
__device__ __forceinline__ float cvtf(float x) { return x; }
__device__ __forceinline__ float cvtf(u16 x) { return b2f(x); }
__device__ __forceinline__ void storef(float* p, float v) { *p = v; }
__device__ __forceinline__ void storef(u16* p, float v) { *p = f2b(v); }
__device__ __forceinline__ float sigf(float x) { return 1.f / (1.f + expf(-x)); }
// dot of one uint4 (8 packed bf16) against 8 floats at p (LDS)
__device__ __forceinline__ float dotq(uint4 q, const float* p) {
    float4 a = *(const float4*)p;
    float4 b = *(const float4*)(p + 4);
    return lo16(q.x) * a.x + hi16(q.x) * a.y + lo16(q.y) * a.z + hi16(q.y) * a.w
         + lo16(q.z) * b.x + hi16(q.z) * b.y + lo16(q.w) * b.z + hi16(q.w) * b.w;
}
// 8-lane group reduce (lanes differing in bits 0..2)
__device__ __forceinline__ float red8(float a) {
    a += __shfl_xor(a, 1);
    a += __shfl_xor(a, 2);
    a += __shfl_xor(a, 4);
    return a;
}
// agent-scope (device-coherent) load/store — no fence needed, no L2 flush
__device__ __forceinline__ void ast(float* p, float v) {
    __hip_atomic_store(p, v, __ATOMIC_RELAXED, __HIP_MEMORY_SCOPE_AGENT);
}
__device__ __forceinline__ float ald(const float* p) {
    return __hip_atomic_load((float*)p, __ATOMIC_RELAXED, __HIP_MEMORY_SCOPE_AGENT);
}

// ---------- dtype-world detector (proven) ----------
__global__ void k_detect(const void* __restrict__ emb, int* __restrict__ flag) {
    __shared__ int s;
    if (threadIdx.x == 0) s = 0;
    __syncthreads();
    const u16* p = (const u16*)emb;
    int bad = 0;
    for (int i = threadIdx.x; i < 8192; i += 256) {
        float v = b2f(p[i]);
        if (!(fabsf(v) < 1e4f)) bad = 1;
    }
    if (bad) s = 1;
    __syncthreads();
    if (threadIdx.x == 0) *flag = s;
}

// ---------- weight canonicalizer ----------
__global__ void k_conv(const void* __restrict__ src, u16* __restrict__ dst, int n,
                       const int* __restrict__ flag) {
    int i = blockIdx.x * 256 + threadIdx.x;
    if (i >= n) return;
    if (*flag) dst[i] = f2b(((const float*)src)[i]);
    else       dst[i] = ((const u16*)src)[i];
}

// ---------- embedding gather -> internal bf16 ----------
__global__ void k_embed(const int* __restrict__ tok, const void* __restrict__ emb,
                        u16* __restrict__ out, const int* __restrict__ flag) {
    int row = blockIdx.x;
    int e = threadIdx.x;
    int v = tok[row];
    u16 r;
    if (*flag) r = f2b(((const float*)emb)[(size_t)v * 256 + e]);
    else       r = ((const u16*)emb)[(size_t)v * 256 + e];
    out[(size_t)row * 256 + e] = r;
}

// ---------- generic GEMM: C[m][n] = sum_k A[m][k]*B[n][k] (+bias[n]) ----------
template <typename TA, typename TC>
__global__ __launch_bounds__(256) void k_gemm_nt(
    const TA* __restrict__ A, int lda,
    const u16* __restrict__ B, int ldb,
    const u16* __restrict__ bias,
    TC* __restrict__ C, int ldc,
    int M, int N, int K) {
    __shared__ float As[32][68];
    __shared__ float Bs[32][68];
    const int bm = blockIdx.y * 64, bn = blockIdx.x * 64;
    const int tid = threadIdx.x;
    const int tm = (tid & 15) * 4, tn = (tid >> 4) * 4;
    float acc[4][4] = {};
    const int ml = tid >> 2, kl = (tid & 3) * 8;
    for (int k0 = 0; k0 < K; k0 += 32) {
        {
            float v[8];
            if (bm + ml < M) {
                const TA* ap = A + (size_t)(bm + ml) * lda + (k0 + kl);
#pragma unroll
                for (int i = 0; i < 8; i++) v[i] = cvtf(ap[i]);
            } else {
#pragma unroll
                for (int i = 0; i < 8; i++) v[i] = 0.f;
            }
#pragma unroll
            for (int i = 0; i < 8; i++) As[kl + i][ml] = v[i];
        }
        {
            float v[8];
            if (bn + ml < N) {
                const u16* bp = B + (size_t)(bn + ml) * ldb + (k0 + kl);
#pragma unroll
                for (int i = 0; i < 8; i++) v[i] = b2f(bp[i]);
            } else {
#pragma unroll
                for (int i = 0; i < 8; i++) v[i] = 0.f;
            }
#pragma unroll
            for (int i = 0; i < 8; i++) Bs[kl + i][ml] = v[i];
        }
        __syncthreads();
#pragma unroll
        for (int k = 0; k < 32; k++) {
            float4 av = *(const float4*)&As[k][tm];
            float4 bv = *(const float4*)&Bs[k][tn];
            acc[0][0] += av.x * bv.x; acc[0][1] += av.x * bv.y; acc[0][2] += av.x * bv.z; acc[0][3] += av.x * bv.w;
            acc[1][0] += av.y * bv.x; acc[1][1] += av.y * bv.y; acc[1][2] += av.y * bv.z; acc[1][3] += av.y * bv.w;
            acc[2][0] += av.z * bv.x; acc[2][1] += av.z * bv.y; acc[2][2] += av.z * bv.z; acc[2][3] += av.z * bv.w;
            acc[3][0] += av.w * bv.x; acc[3][1] += av.w * bv.y; acc[3][2] += av.w * bv.z; acc[3][3] += av.w * bv.w;
        }
        __syncthreads();
    }
#pragma unroll
    for (int i = 0; i < 4; i++) {
        int m = bm + tm + i;
        if (m >= M) continue;
#pragma unroll
        for (int j = 0; j < 4; j++) {
            int n = bn + tn + j;
            float v = acc[i][j];
            if (bias) v += b2f(bias[n]);
            storef(&C[(size_t)m * ldc + n], v);
        }
    }
}

// ---------- group barrier: monotonic counter (padded line), agent-scope ----------
__device__ __forceinline__ void gbar(int* c, int target) {
    __syncthreads();  // all waves drain their stores (vmcnt) before flag
    if (threadIdx.x == 0) {
        __hip_atomic_fetch_add(c, 1, __ATOMIC_RELAXED, __HIP_MEMORY_SCOPE_AGENT);
        while (__hip_atomic_load(c, __ATOMIC_RELAXED, __HIP_MEMORY_SCOPE_AGENT) < target)
            __builtin_amdgcn_s_sleep(2);
    }
    __syncthreads();
}

// ---------- multi-block encoder v3 (r26, proven) ----------
__global__ __launch_bounds__(512) void k_enc_mb(
    const u16* __restrict__ Xf, const u16* __restrict__ Xb,
    const u16* __restrict__ Whh_f, const u16* __restrict__ Whh_b,
    u16* __restrict__ enc, float* __restrict__ hFB,
    float* __restrict__ gbe, int* __restrict__ cnte) {
    const int chain = blockIdx.x & 63, gi = blockIdx.x >> 6;
    const int d = chain >> 5, b = chain & 31;
    const int j = threadIdx.x;
    const int q = j & 7, r8i = j >> 3;
    __shared__ u16 whl[256 * 264];
    __shared__ float hs[256];
    __shared__ float gall4[4][64];
    const u16* W = d ? Whh_b : Whh_f;
    for (int idx = j; idx < 8192; idx += 512) {
        int row = idx >> 5, kc = idx & 31;
        int grow = (row >> 6) * 256 + gi * 64 + (row & 63);
        *(uint4*)&whl[row * 264 + kc * 8] =
            *(const uint4*)(W + (size_t)grow * 256 + kc * 8);
    }
    float c = 0.f;
    if (j < 256) hs[j] = 0.f;
    __syncthreads();
    const u16* Xd = d ? Xb : Xf;
    float* hb = gbe + (size_t)chain * 512;
    int* cc = cnte + chain * 32;
    for (int step = 0; step < 512; step++) {
        const int pos = d ? (511 - step) : step;
        const u16* xp = Xd + ((size_t)pos * 32 + b) * 1024;
#pragma unroll 2
        for (int it = 0; it < 4; it++) {
            const u16* wr = &whl[(it * 64 + r8i) * 264];
            float a0 = 0.f, a1 = 0.f;
#pragma unroll
            for (int i = 0; i < 4; i += 2) {
                int u0 = q + 8 * i, u1 = q + 8 * (i + 1);
                a0 += dotq(*(const uint4*)(wr + u0 * 8), &hs[u0 * 8]);
                a1 += dotq(*(const uint4*)(wr + u1 * 8), &hs[u1 * 8]);
            }
            float a = red8(a0 + a1);
            if (q == 0) gall4[it][r8i] = a + b2f(xp[it * 256 + gi * 64 + r8i]);
        }
        __syncthreads();
        if (j < 64) {
            int jj = gi * 64 + j;
            float ig = sigf(gall4[0][j]), fg = sigf(gall4[1][j]);
            float gg = tanhf(gall4[2][j]), og = sigf(gall4[3][j]);
            c = fg * c + ig * gg;
            float h = og * tanhf(c);
            ast(&hb[(step & 1) * 256 + jj], h);
            enc[((size_t)b * 512 + pos) * 512 + (size_t)d * 256 + jj] = f2b(h);
        }
        gbar(cc, 4 * (step + 1));
        if (j < 256) hs[j] = ald(&hb[(step & 1) * 256 + j]);
        __syncthreads();
    }
    if (gi == 0 && j < 256) hFB[(size_t)b * 512 + (size_t)d * 256 + j] = hs[j];
}

// ---------- multi-block decoder v7: 256 blocks (32 batches x 8 groups) x 512 thr ----------
// proj = enc@Watt^T precomputed; own 64-row enc+proj slices in LDS.
// Per step: A) gates for own 32 j's (2 sweeps) -> publish 32 h floats; barrier;
// B') e via projl (1 sweep, 256-dot) + evsum/ctx partials; barrier;
// D) 8-way ctx gather + full redundant o_t (4 sweeps).
__global__ __launch_bounds__(512) void k_dec_mb(
    const u16* __restrict__ Ypart,
    const u16* __restrict__ Whh_d, const u16* __restrict__ Wih_d,
    const u16* __restrict__ projg, const u16* __restrict__ Wcomb,
    const u16* __restrict__ enc,
    const float* __restrict__ ht0, const float* __restrict__ ct0,
    float* __restrict__ hid,
    float* __restrict__ hbd, float* __restrict__ evsum,
    float* __restrict__ pctx, int* __restrict__ cnt) {
    const int b = blockIdx.x & 31, gi = blockIdx.x >> 5;  // gi 0..7
    const int j = threadIdx.x;
    const int q = j & 7, r8i = j >> 3;   // 8 lanes/row, r8i 0..63
    const int wv = j >> 6, ln = j & 63;  // 8 waves
    __shared__ u16 encl[64 * 520];       // own enc rows [gi*64,+64)
    __shared__ u16 projl[64 * 264];      // own proj rows
    __shared__ float hs[256], os[256];
    __shared__ float evl[64];
    __shared__ float pctxw[8][520];
    __shared__ float hc[768];
    __shared__ float redw[8];
    __shared__ float gall[128];
    float c = 0.f;
    if (j < 256) {
        hs[j] = ht0[(size_t)b * 256 + j];
        os[j] = 0.f;
    }
    if (j < 32) c = ct0[(size_t)b * 256 + gi * 32 + j];
    {
        const uint4* encb = (const uint4*)(enc + (size_t)b * 512 * 512);
        for (int idx = j; idx < 4096; idx += 512) {  // 64 rows x 64 quads
            int row = idx >> 6, kc = idx & 63;
            *(uint4*)&encl[row * 520 + kc * 8] = encb[(size_t)(gi * 64 + row) * 64 + kc];
        }
        const uint4* projb = (const uint4*)(projg + (size_t)b * 512 * 256);
        for (int idx = j; idx < 2048; idx += 512) {  // 64 rows x 32 quads
            int row = idx >> 5, kc = idx & 31;
            *(uint4*)&projl[row * 264 + kc * 8] = projb[(size_t)(gi * 64 + row) * 32 + kc];
        }
    }
    __syncthreads();
    float* hb = hbd + (size_t)b * 512;
    int* c0 = cnt + b * 32;
    for (int s = 0; s < 127; s++) {
        const int tgt = 8 * (s + 1);
        const u16* yp = Ypart + ((size_t)s * 32 + b) * 1024;
        // ---- A: 128 gate rows (4 gates x own 32 j's), 2 sweeps ----
#pragma unroll
        for (int it = 0; it < 2; it++) {
            int rl = it * 64 + r8i;                 // 0..127
            int gate = rl >> 5, jj = gi * 32 + (rl & 31);
            int row = gate * 256 + jj;
            const uint4* wh = (const uint4*)(Whh_d + (size_t)row * 256);
            const uint4* wo = (const uint4*)(Wih_d + (size_t)row * 512 + 256);
            float ah = 0.f, ao = 0.f;
#pragma unroll
            for (int i = 0; i < 4; i++) {
                int u = q + 8 * i;
                ah += dotq(wh[u], &hs[u * 8]);
                ao += dotq(wo[u], &os[u * 8]);
            }
            float a = red8(ah + ao);
            if (q == 0) gall[rl] = a + b2f(yp[row]);
        }
        __syncthreads();
        if (j < 32) {
            int jj = gi * 32 + j;
            float ig = sigf(gall[j]), fg = sigf(gall[32 + j]);
            float gg = tanhf(gall[64 + j]), og = sigf(gall[96 + j]);
            c = fg * c + ig * gg;
            float h = og * tanhf(c);
            ast(&hb[(s & 1) * 256 + jj], h);
        }
        gbar(c0, tgt);
        if (j < 256) hs[j] = ald(&hb[(s & 1) * 256 + j]);
        __syncthreads();
        // ---- B': e for own 64 rows via projl (1 sweep, 256-dot) ----
        {
            const u16* pr = &projl[r8i * 264];
            float a0 = 0.f, a1 = 0.f;
#pragma unroll
            for (int i = 0; i < 4; i += 2) {
                int u0 = q + 8 * i, u1 = q + 8 * (i + 1);
                a0 += dotq(*(const uint4*)(pr + u0 * 8), &hs[u0 * 8]);
                a1 += dotq(*(const uint4*)(pr + u1 * 8), &hs[u1 * 8]);
            }
            float a = red8(a0 + a1);
            if (q == 0) evl[r8i] = expf(a);
        }
        __syncthreads();
        if (j < 64) {  // exp-sum over own 64 rows (wave 0)
            float v = evl[j];
            for (int off = 32; off; off >>= 1) v += __shfl_down(v, off);
            if (j == 0) ast(&evsum[b * 16 + gi], v);
        }
        // ---- ctx partial: wave wv handles 8 rows ----
        {
            float a0 = 0, a1 = 0, a2 = 0, a3 = 0, a4 = 0, a5 = 0, a6 = 0, a7 = 0;
#pragma unroll
            for (int rr = 0; rr < 8; rr++) {
                int lrow = wv * 8 + rr;
                uint4 qd = *(const uint4*)&encl[lrow * 520 + ln * 8];
                float w = evl[lrow];
                a0 += w * lo16(qd.x); a1 += w * hi16(qd.x);
                a2 += w * lo16(qd.y); a3 += w * hi16(qd.y);
                a4 += w * lo16(qd.z); a5 += w * hi16(qd.z);
                a6 += w * lo16(qd.w); a7 += w * hi16(qd.w);
            }
            float* pw = &pctxw[wv][ln * 8];
            pw[0] = a0; pw[1] = a1; pw[2] = a2; pw[3] = a3;
            pw[4] = a4; pw[5] = a5; pw[6] = a6; pw[7] = a7;
        }
        __syncthreads();
        if (j < 512) {
            float p = 0.f;
#pragma unroll
            for (int w = 0; w < 8; w++) p += pctxw[w][j];
            ast(&pctx[((size_t)b * 8 + gi) * 512 + j], p);
        }
        gbar(c0 + 16, tgt);
        // ---- D: 8-way ctx gather + full redundant o_t ----
        if (j < 8) redw[j] = ald(&evsum[b * 16 + j]);
        if (j < 256) hc[j] = hs[j];
        __syncthreads();
        {
            const float* pc = pctx + (size_t)b * 8 * 512;
            float v = 0.f;
#pragma unroll
            for (int g2 = 0; g2 < 8; g2++) v += ald(&pc[g2 * 512 + j]);
            float inv = 1.f / (redw[0] + redw[1] + redw[2] + redw[3] +
                               redw[4] + redw[5] + redw[6] + redw[7]);
            hc[256 + j] = v * inv;
        }
        __syncthreads();
#pragma unroll 2
        for (int it = 0; it < 4; it++) {
            int row = it * 64 + r8i;
            const uint4* wc = (const uint4*)(Wcomb + (size_t)row * 768);
            float a0 = 0.f, a1 = 0.f;
#pragma unroll
            for (int i = 0; i < 12; i += 2) {
                int u0 = q + 8 * i, u1 = q + 8 * (i + 1);
                a0 += dotq(wc[u0], &hc[u0 * 8]);
                a1 += dotq(wc[u1], &hc[u1 * 8]);
            }
            float a = red8(a0 + a1);
            if (q == 0) {
                float o = tanhf(a);
                os[row] = o;
                if (gi == 0) hid[((size_t)s * 32 + b) * 256 + row] = o;
            }
        }
        __syncthreads();
    }
}

// ---------- logit at target index ----------
__global__ __launch_bounds__(256) void k_lidx(
    const int* __restrict__ target, const float* __restrict__ hid,
    const void* __restrict__ WvocV, float* __restrict__ lidx,
    const int* __restrict__ flag) {
    int p = blockIdx.x * 4 + (threadIdx.x >> 6);
    if (p >= 127 * 32) return;
    int lane = threadIdx.x & 63;
    int t = p >> 5, b = p & 31;
    int idx = target[(t + 1) * 32 + b];
    const float* h = hid + (size_t)p * 256;
    const bool f32w = (*flag != 0);
    float a = 0.f;
#pragma unroll
    for (int i = 0; i < 4; i++) {
        int k = lane * 4 + i;
        float wv = f32w ? ((const float*)WvocV)[(size_t)idx * 256 + k]
                        : b2f(((const u16*)WvocV)[(size_t)idx * 256 + k]);
        a += h[k] * wv;
    }
    for (int off = 32; off; off >>= 1) a += __shfl_down(a, off);
    if (lane == 0) lidx[p] = a;
}

// ---------- sumexp v4 (r27, MFMA, proven) ----------
__global__ __launch_bounds__(256) void k_sumexp(
    const float* __restrict__ hid, const void* __restrict__ WvocV,
    float* __restrict__ psum, const int* __restrict__ flag) {
    const int cb = blockIdx.x * 128;
    const int tid = threadIdx.x;
    const bool f32w = (*flag != 0);
    __shared__ u16 Wl[128 * 264];
    __shared__ u16 Hsb[32 * 264];
    __shared__ float red[32][2];
    for (int idx = tid; idx < 4096; idx += 256) {
        int col = idx >> 5, kc = idx & 31;
        uint4 val;
        if (f32w) {
            const float4* src = (const float4*)((const float*)WvocV + (size_t)(cb + col) * 256 + kc * 8);
            float4 f0 = src[0], f1 = src[1];
            u16 h[8];
            h[0] = f2b(f0.x); h[1] = f2b(f0.y); h[2] = f2b(f0.z); h[3] = f2b(f0.w);
            h[4] = f2b(f1.x); h[5] = f2b(f1.y); h[6] = f2b(f1.z); h[7] = f2b(f1.w);
            val = *(const uint4*)h;
        } else {
            val = *(const uint4*)((const u16*)WvocV + (size_t)(cb + col) * 256 + kc * 8);
        }
        *(uint4*)&Wl[col * 264 + kc * 8] = val;
    }
    const int wave = tid >> 6, lane = tid & 63;
    const int mtile = wave & 1;
    const int n0base = (wave >> 1) * 64;
    const int fr = lane & 15, fk = (lane >> 4) * 8;
    const int drow = mtile * 16 + (lane >> 4) * 4;
    for (int it = 0; it < 127; it++) {
        const int gr = it * 32;
        __syncthreads();
        for (int idx = tid; idx < 1024; idx += 256) {
            int row = idx >> 5, kq = idx & 31;
            const float4* hp = (const float4*)(hid + (size_t)(gr + row) * 256 + kq * 8);
            float4 f0 = hp[0], f1 = hp[1];
            u16 h[8];
            h[0] = f2b(f0.x); h[1] = f2b(f0.y); h[2] = f2b(f0.z); h[3] = f2b(f0.w);
            h[4] = f2b(f1.x); h[5] = f2b(f1.y); h[6] = f2b(f1.z); h[7] = f2b(f1.w);
            *(uint4*)&Hsb[row * 264 + kq * 8] = *(const uint4*)h;
        }
        __syncthreads();
        bf16x8 afr[8];
#pragma unroll
        for (int kc = 0; kc < 8; kc++)
            afr[kc] = *(const bf16x8*)&Hsb[(mtile * 16 + fr) * 264 + kc * 32 + fk];
        float es[4] = {0.f, 0.f, 0.f, 0.f};
#pragma unroll
        for (int nt = 0; nt < 4; nt++) {
            f32x4 acc = {0.f, 0.f, 0.f, 0.f};
            const u16* bbase = &Wl[(n0base + nt * 16 + fr) * 264 + fk];
#pragma unroll
            for (int kc = 0; kc < 8; kc++) {
                bf16x8 bfr = *(const bf16x8*)(bbase + kc * 32);
                acc = __builtin_amdgcn_mfma_f32_16x16x32_bf16(afr[kc], bfr, acc, 0, 0, 0);
            }
#pragma unroll
            for (int r = 0; r < 4; r++) es[r] += expf(acc[r]);
        }
#pragma unroll
        for (int r = 0; r < 4; r++) {
            float v = es[r];
            v += __shfl_xor(v, 1);
            v += __shfl_xor(v, 2);
            v += __shfl_xor(v, 4);
            v += __shfl_xor(v, 8);
            if ((lane & 15) == 0) red[drow + r][wave >> 1] = v;
        }
        __syncthreads();
        if (tid < 32) atomicAdd(&psum[gr + tid], red[tid][0] + red[tid][1]);
    }
}

// ---------- final scores ----------
__global__ void k_scores(const int* __restrict__ target, const float* __restrict__ lidx,
                         const float* __restrict__ psum, void* __restrict__ outv,
                         const int* __restrict__ flag) {
    int b = threadIdx.x;
    if (b >= 32) return;
    float acc = 0.f;
    for (int t = 0; t < 127; t++) {
        int idx = target[(t + 1) * 32 + b];
        if (idx != 0) {
            int row = t * 32 + b;
            acc += lidx[row] - logf(psum[row]);
        }
    }
    if (*flag) ((float*)outv)[b] = acc;
    else       ((u16*)outv)[b] = f2b(acc);
}

extern "C" void kernel_launch(void* const* d_in, const int* in_sizes, int n_in,
                              void* d_out, int out_size, void* d_ws, size_t ws_size,
                              hipStream_t stream) {
    const int* source = (const int*)d_in[0];
    const int* target = (const int*)d_in[1];
    const void* src_emb = d_in[2];
    const void* tgt_emb = d_in[3];
    const void* Wih_f = d_in[4];
    const void* Whh_f = d_in[5];
    const void* b_f = d_in[6];
    const void* Wih_b = d_in[7];
    const void* Whh_b = d_in[8];
    const void* b_b = d_in[9];
    const void* Wih_d = d_in[10];
    const void* Whh_d = d_in[11];
    const void* b_d = d_in[12];
    const void* Wh = d_in[13];
    const void* Wc = d_in[14];
    const void* Watt = d_in[15];
    const void* Wcomb = d_in[16];
    const void* Wvoc = d_in[17];

    // ---- workspace layout: [flag pad][f32 buffers][u16 buffers] ----
    int* flag = (int*)d_ws;
    float* fw = (float*)d_ws;
    size_t off = 64;
    float* hid = fw + off;    off += (size_t)127 * 32 * 256;
    float* hFB = fw + off;    off += (size_t)32 * 512;
    float* ht0 = fw + off;    off += (size_t)32 * 256;
    float* ct0 = fw + off;    off += (size_t)32 * 256;
    float* lidx = fw + off;   off += 4096;
    float* psum = fw + off;   off += 4096;
    float* hbd = fw + off;    off += (size_t)32 * 512;
    float* evsum = fw + off;  off += 512;
    float* pctx = fw + off;   off += (size_t)32 * 8 * 512;
    float* gbe = fw + off;    off += (size_t)64 * 512;
    int* cnt = (int*)(fw + off); off += 1024;
    int* cnte = (int*)(fw + off); off += 2048;
    u16* ub = (u16*)(fw + off);
    size_t uo = 0;
    u16* X = ub + uo;       uo += (size_t)512 * 32 * 256;
    u16* Yemb = ub + uo;    uo += (size_t)127 * 32 * 256;
    u16* Xf = ub + uo;      uo += (size_t)512 * 32 * 1024;
    u16* Xb = ub + uo;      uo += (size_t)512 * 32 * 1024;
    u16* Ypart = ub + uo;   uo += (size_t)127 * 32 * 1024;
    u16* enc_p = ub + uo;   uo += (size_t)32 * 512 * 512;
    u16* proj = ub + uo;    uo += (size_t)32 * 512 * 256;
    u16* cWatt = ub + uo;   uo += 131072;
    u16* cWih_f = ub + uo;  uo += 262144;
    u16* cWhh_f = ub + uo;  uo += 262144;
    u16* cb_f = ub + uo;    uo += 1024;
    u16* cWih_b = ub + uo;  uo += 262144;
    u16* cWhh_b = ub + uo;  uo += 262144;
    u16* cb_b = ub + uo;    uo += 1024;
    u16* cWih_d = ub + uo;  uo += 524288;
    u16* cWhh_d = ub + uo;  uo += 262144;
    u16* cb_d = ub + uo;    uo += 1024;
    u16* cWh = ub + uo;     uo += 131072;
    u16* cWc = ub + uo;     uo += 131072;
    u16* cWcomb = ub + uo;  uo += 196608;
    size_t needed = off * 4 + uo * 2;
    if (ws_size < needed) return;

    // 0. detect dtype world, canonicalize weights
    k_detect<<<1, 256, 0, stream>>>(src_emb, flag);
    auto conv = [&](const void* s, u16* d, int n) {
        k_conv<<<(n + 255) / 256, 256, 0, stream>>>(s, d, n, flag);
    };
    conv(Wih_f, cWih_f, 262144);  conv(Whh_f, cWhh_f, 262144);  conv(b_f, cb_f, 1024);
    conv(Wih_b, cWih_b, 262144);  conv(Whh_b, cWhh_b, 262144);  conv(b_b, cb_b, 1024);
    conv(Wih_d, cWih_d, 524288);  conv(Whh_d, cWhh_d, 262144);  conv(b_d, cb_d, 1024);
    conv(Wh, cWh, 131072);        conv(Wc, cWc, 131072);
    conv(Watt, cWatt, 131072);    conv(Wcomb, cWcomb, 196608);

    // 1. embed source
    k_embed<<<512 * 32, 256, 0, stream>>>(source, src_emb, X, flag);
    // 2. x-part gate preactivations, both directions (bf16 out)
    k_gemm_nt<u16, u16><<<dim3(16, 256), 256, 0, stream>>>(X, 256, cWih_f, 256, cb_f, Xf, 1024, 16384, 1024, 256);
    k_gemm_nt<u16, u16><<<dim3(16, 256), 256, 0, stream>>>(X, 256, cWih_b, 256, cb_b, Xb, 1024, 16384, 1024, 256);
    // 3. multi-block encoder v3
    hipMemsetAsync(cnte, 0, 2048 * sizeof(int), stream);
    k_enc_mb<<<256, 512, 0, stream>>>(Xf, Xb, cWhh_f, cWhh_b, enc_p, hFB, gbe, cnte);
    // 3b. attention projection proj = enc @ Watt^T (reference enc_hiddens_proj)
    k_gemm_nt<u16, u16><<<dim3(4, 256), 256, 0, stream>>>(enc_p, 512, cWatt, 512, (const u16*)nullptr, proj, 256, 16384, 256, 512);
    // 4. initial decoder state
    k_gemm_nt<float, float><<<dim3(4, 1), 256, 0, stream>>>(hFB, 512, cWh, 512, (const u16*)nullptr, ht0, 256, 32, 256, 512);
    k_gemm_nt<float, float><<<dim3(4, 1), 256, 0, stream>>>(hFB, 512, cWc, 512, (const u16*)nullptr, ct0, 256, 32, 256, 512);
    // 5. embed target + decoder y-part preactivations (bf16 out)
    k_embed<<<127 * 32, 256, 0, stream>>>(target, tgt_emb, Yemb, flag);
    k_gemm_nt<u16, u16><<<dim3(16, 64), 256, 0, stream>>>(Yemb, 256, cWih_d, 512, cb_d, Ypart, 1024, 4064, 1024, 256);
    // 6. multi-block decoder v7 (proj in LDS, 8 groups/batch)
    hipMemsetAsync(cnt, 0, 1024 * sizeof(int), stream);
    k_dec_mb<<<256, 512, 0, stream>>>(Ypart, cWhh_d, cWih_d, proj, cWcomb, enc_p,
                                      ht0, ct0, hid, hbd, evsum, pctx, cnt);
    // 7. scores (MFMA sumexp)
    hipMemsetAsync(psum, 0, 4096 * sizeof(float), stream);
    k_lidx<<<(127 * 32 + 3) / 4, 256, 0, stream>>>(target, hid, Wvoc, lidx, flag);
    k_sumexp<<<250, 256, 0, stream>>>(hid, Wvoc, psum, flag);
    k_scores<<<1, 64, 0, stream>>>(target, lidx, psum, d_out, flag);
}

// Round 29
// 4545.814 us; speedup vs baseline: 1.3089x; 1.3089x over previous
//
#include <hip/hip_runtime.h>
#include <hip/hip_bf16.h>
#include <math.h>

typedef unsigned int u32;
typedef unsigned short u16;
typedef __attribute__((ext_vector_type(8))) short bf16x8;
typedef __attribute__((ext_vector_type(4))) float f32x4;

// ---------- bf16 helpers ----------
__device__ __forceinline__ float bfbits(u32 hi) { union { u32 u; float f; } v; v.u = hi; return v.f; }
__device__ __forceinline__ float lo16(u32 p) { return bfbits(p << 16); }
__device__ __forceinline__ float hi16(u32 p) { return bfbits(p & 0xffff0000u); }
__device__ __forceinline__ float b2f(u16 x) { return bfbits(((u32)x) << 16); }
__device__ __forceinline__ u16 f2b(float f) {
    union { float f; u32 u; } v; v.f = f;
    u32 u = v.u;
    u32 r = (u + 0x7fffu + ((u >> 16) & 1u)) >> 16;  // RNE
    return (u16)r;
}
__device__ __forceinline__ float cvtf(float x) { return x; }
__device__ __forceinline__ float cvtf(u16 x) { return b2f(x); }
__device__ __forceinline__ void storef(float* p, float v) { *p = v; }
__device__ __forceinline__ void storef(u16* p, float v) { *p = f2b(v); }
__device__ __forceinline__ float sigf(float x) { return 1.f / (1.f + expf(-x)); }
// dot of one uint4 (8 packed bf16) against 8 floats at p (LDS)
__device__ __forceinline__ float dotq(uint4 q, const float* p) {
    float4 a = *(const float4*)p;
    float4 b = *(const float4*)(p + 4);
    return lo16(q.x) * a.x + hi16(q.x) * a.y + lo16(q.y) * a.z + hi16(q.y) * a.w
         + lo16(q.z) * b.x + hi16(q.z) * b.y + lo16(q.w) * b.z + hi16(q.w) * b.w;
}
// 8-lane group reduce (lanes differing in bits 0..2)
__device__ __forceinline__ float red8(float a) {
    a += __shfl_xor(a, 1);
    a += __shfl_xor(a, 2);
    a += __shfl_xor(a, 4);
    return a;
}
// agent-scope (device-coherent) load/store — no fence needed, no L2 flush
__device__ __forceinline__ void ast(float* p, float v) {
    __hip_atomic_store(p, v, __ATOMIC_RELAXED, __HIP_MEMORY_SCOPE_AGENT);
}
__device__ __forceinline__ float ald(const float* p) {
    return __hip_atomic_load((float*)p, __ATOMIC_RELAXED, __HIP_MEMORY_SCOPE_AGENT);
}

// ---------- dtype-world detector (proven) ----------
__global__ void k_detect(const void* __restrict__ emb, int* __restrict__ flag) {
    __shared__ int s;
    if (threadIdx.x == 0) s = 0;
    __syncthreads();
    const u16* p = (const u16*)emb;
    int bad = 0;
    for (int i = threadIdx.x; i < 8192; i += 256) {
        float v = b2f(p[i]);
        if (!(fabsf(v) < 1e4f)) bad = 1;
    }
    if (bad) s = 1;
    __syncthreads();
    if (threadIdx.x == 0) *flag = s;
}

// ---------- weight canonicalizer ----------
__global__ void k_conv(const void* __restrict__ src, u16* __restrict__ dst, int n,
                       const int* __restrict__ flag) {
    int i = blockIdx.x * 256 + threadIdx.x;
    if (i >= n) return;
    if (*flag) dst[i] = f2b(((const float*)src)[i]);
    else       dst[i] = ((const u16*)src)[i];
}

// ---------- Watt transpose ----------
__global__ void k_wattT(const void* __restrict__ src, u16* __restrict__ dst,
                        const int* __restrict__ flag) {
    int c = blockIdx.x;   // 0..511
    int r = threadIdx.x;  // 0..255
    u16 v;
    if (*flag) v = f2b(((const float*)src)[(size_t)r * 512 + c]);
    else       v = ((const u16*)src)[(size_t)r * 512 + c];
    dst[(size_t)c * 256 + r] = v;
}

// ---------- embedding gather -> internal bf16 ----------
__global__ void k_embed(const int* __restrict__ tok, const void* __restrict__ emb,
                        u16* __restrict__ out, const int* __restrict__ flag) {
    int row = blockIdx.x;
    int e = threadIdx.x;
    int v = tok[row];
    u16 r;
    if (*flag) r = f2b(((const float*)emb)[(size_t)v * 256 + e]);
    else       r = ((const u16*)emb)[(size_t)v * 256 + e];
    out[(size_t)row * 256 + e] = r;
}

// ---------- generic GEMM: C[m][n] = sum_k A[m][k]*B[n][k] (+bias[n]) ----------
template <typename TA, typename TC>
__global__ __launch_bounds__(256) void k_gemm_nt(
    const TA* __restrict__ A, int lda,
    const u16* __restrict__ B, int ldb,
    const u16* __restrict__ bias,
    TC* __restrict__ C, int ldc,
    int M, int N, int K) {
    __shared__ float As[32][68];
    __shared__ float Bs[32][68];
    const int bm = blockIdx.y * 64, bn = blockIdx.x * 64;
    const int tid = threadIdx.x;
    const int tm = (tid & 15) * 4, tn = (tid >> 4) * 4;
    float acc[4][4] = {};
    const int ml = tid >> 2, kl = (tid & 3) * 8;
    for (int k0 = 0; k0 < K; k0 += 32) {
        {
            float v[8];
            if (bm + ml < M) {
                const TA* ap = A + (size_t)(bm + ml) * lda + (k0 + kl);
#pragma unroll
                for (int i = 0; i < 8; i++) v[i] = cvtf(ap[i]);
            } else {
#pragma unroll
                for (int i = 0; i < 8; i++) v[i] = 0.f;
            }
#pragma unroll
            for (int i = 0; i < 8; i++) As[kl + i][ml] = v[i];
        }
        {
            float v[8];
            if (bn + ml < N) {
                const u16* bp = B + (size_t)(bn + ml) * ldb + (k0 + kl);
#pragma unroll
                for (int i = 0; i < 8; i++) v[i] = b2f(bp[i]);
            } else {
#pragma unroll
                for (int i = 0; i < 8; i++) v[i] = 0.f;
            }
#pragma unroll
            for (int i = 0; i < 8; i++) Bs[kl + i][ml] = v[i];
        }
        __syncthreads();
#pragma unroll
        for (int k = 0; k < 32; k++) {
            float4 av = *(const float4*)&As[k][tm];
            float4 bv = *(const float4*)&Bs[k][tn];
            acc[0][0] += av.x * bv.x; acc[0][1] += av.x * bv.y; acc[0][2] += av.x * bv.z; acc[0][3] += av.x * bv.w;
            acc[1][0] += av.y * bv.x; acc[1][1] += av.y * bv.y; acc[1][2] += av.y * bv.z; acc[1][3] += av.y * bv.w;
            acc[2][0] += av.z * bv.x; acc[2][1] += av.z * bv.y; acc[2][2] += av.z * bv.z; acc[2][3] += av.z * bv.w;
            acc[3][0] += av.w * bv.x; acc[3][1] += av.w * bv.y; acc[3][2] += av.w * bv.z; acc[3][3] += av.w * bv.w;
        }
        __syncthreads();
    }
#pragma unroll
    for (int i = 0; i < 4; i++) {
        int m = bm + tm + i;
        if (m >= M) continue;
#pragma unroll
        for (int j = 0; j < 4; j++) {
            int n = bn + tn + j;
            float v = acc[i][j];
            if (bias) v += b2f(bias[n]);
            storef(&C[(size_t)m * ldc + n], v);
        }
    }
}

// ---------- group barrier: monotonic counter (padded line), agent-scope ----------
__device__ __forceinline__ void gbar(int* c, int target) {
    __syncthreads();  // all waves drain their stores (vmcnt) before flag
    if (threadIdx.x == 0) {
        __hip_atomic_fetch_add(c, 1, __ATOMIC_RELAXED, __HIP_MEMORY_SCOPE_AGENT);
        while (__hip_atomic_load(c, __ATOMIC_RELAXED, __HIP_MEMORY_SCOPE_AGENT) < target)
            __builtin_amdgcn_s_sleep(2);
    }
    __syncthreads();
}

// ---------- multi-block encoder v3 (r26, proven) ----------
__global__ __launch_bounds__(512) void k_enc_mb(
    const u16* __restrict__ Xf, const u16* __restrict__ Xb,
    const u16* __restrict__ Whh_f, const u16* __restrict__ Whh_b,
    u16* __restrict__ enc, float* __restrict__ hFB,
    float* __restrict__ gbe, int* __restrict__ cnte) {
    const int chain = blockIdx.x & 63, gi = blockIdx.x >> 6;
    const int d = chain >> 5, b = chain & 31;
    const int j = threadIdx.x;
    const int q = j & 7, r8i = j >> 3;
    __shared__ u16 whl[256 * 264];
    __shared__ float hs[256];
    __shared__ float gall4[4][64];
    const u16* W = d ? Whh_b : Whh_f;
    for (int idx = j; idx < 8192; idx += 512) {
        int row = idx >> 5, kc = idx & 31;
        int grow = (row >> 6) * 256 + gi * 64 + (row & 63);
        *(uint4*)&whl[row * 264 + kc * 8] =
            *(const uint4*)(W + (size_t)grow * 256 + kc * 8);
    }
    float c = 0.f;
    if (j < 256) hs[j] = 0.f;
    __syncthreads();
    const u16* Xd = d ? Xb : Xf;
    float* hb = gbe + (size_t)chain * 512;
    int* cc = cnte + chain * 32;
    for (int step = 0; step < 512; step++) {
        const int pos = d ? (511 - step) : step;
        const u16* xp = Xd + ((size_t)pos * 32 + b) * 1024;
#pragma unroll 2
        for (int it = 0; it < 4; it++) {
            const u16* wr = &whl[(it * 64 + r8i) * 264];
            float a0 = 0.f, a1 = 0.f;
#pragma unroll
            for (int i = 0; i < 4; i += 2) {
                int u0 = q + 8 * i, u1 = q + 8 * (i + 1);
                a0 += dotq(*(const uint4*)(wr + u0 * 8), &hs[u0 * 8]);
                a1 += dotq(*(const uint4*)(wr + u1 * 8), &hs[u1 * 8]);
            }
            float a = red8(a0 + a1);
            if (q == 0) gall4[it][r8i] = a + b2f(xp[it * 256 + gi * 64 + r8i]);
        }
        __syncthreads();
        if (j < 64) {
            int jj = gi * 64 + j;
            float ig = sigf(gall4[0][j]), fg = sigf(gall4[1][j]);
            float gg = tanhf(gall4[2][j]), og = sigf(gall4[3][j]);
            c = fg * c + ig * gg;
            float h = og * tanhf(c);
            ast(&hb[(step & 1) * 256 + jj], h);
            enc[((size_t)b * 512 + pos) * 512 + (size_t)d * 256 + jj] = f2b(h);
        }
        gbar(cc, 4 * (step + 1));
        if (j < 256) hs[j] = ald(&hb[(step & 1) * 256 + j]);
        __syncthreads();
    }
    if (gi == 0 && j < 256) hFB[(size_t)b * 512 + (size_t)d * 256 + j] = hs[j];
}

// ---------- multi-block decoder v6 (r26/r27, proven) ----------
__global__ __launch_bounds__(512) void k_dec_mb(
    const u16* __restrict__ Ypart,
    const u16* __restrict__ Whh_d, const u16* __restrict__ Wih_d,
    const u16* __restrict__ WattT, const u16* __restrict__ Wcomb,
    const u16* __restrict__ enc,
    const float* __restrict__ ht0, const float* __restrict__ ct0,
    float* __restrict__ hid,
    float* __restrict__ hbd, float* __restrict__ evsum,
    float* __restrict__ pctx, int* __restrict__ cnt) {
    const int b = blockIdx.x & 31, gi = blockIdx.x >> 5;
    const int j = threadIdx.x;
    const int q = j & 7, r8i = j >> 3;
    const int wv = j >> 6, ln = j & 63;
    __shared__ u16 encl[128 * 520];
    __shared__ float hs[256], os[256];
    __shared__ float g[512];
    __shared__ float evl[128];
    __shared__ float pctxw[8][520];
    __shared__ float hc[768];
    __shared__ float redw[8];
    __shared__ float gall4[4][64];
    float c = 0.f;
    if (j < 256) {
        hs[j] = ht0[(size_t)b * 256 + j];
        os[j] = 0.f;
    }
    if (j < 64) c = ct0[(size_t)b * 256 + gi * 64 + j];
    {
        const uint4* encb = (const uint4*)(enc + (size_t)b * 512 * 512);
        for (int idx = j; idx < 8192; idx += 512) {
            int row = idx >> 6, kc = idx & 63;
            *(uint4*)&encl[row * 520 + kc * 8] = encb[(size_t)(gi * 128 + row) * 64 + kc];
        }
    }
    __syncthreads();
    float* hb = hbd + (size_t)b * 512;
    int* c0 = cnt + b * 32;
    for (int s = 0; s < 127; s++) {
        const int tgt = 4 * (s + 1);
        const u16* yp = Ypart + ((size_t)s * 32 + b) * 1024;
#pragma unroll 2
        for (int it = 0; it < 4; it++) {
            int row = it * 256 + gi * 64 + r8i;
            const uint4* wh = (const uint4*)(Whh_d + (size_t)row * 256);
            const uint4* wo = (const uint4*)(Wih_d + (size_t)row * 512 + 256);
            float ah = 0.f, ao = 0.f;
#pragma unroll
            for (int i = 0; i < 4; i++) {
                int u = q + 8 * i;
                ah += dotq(wh[u], &hs[u * 8]);
                ao += dotq(wo[u], &os[u * 8]);
            }
            float a = red8(ah + ao);
            if (q == 0) gall4[it][r8i] = a + b2f(yp[row]);
        }
        __syncthreads();
        if (j < 64) {
            int jj = gi * 64 + j;
            float ig = sigf(gall4[0][j]), fg = sigf(gall4[1][j]);
            float gg = tanhf(gall4[2][j]), og = sigf(gall4[3][j]);
            c = fg * c + ig * gg;
            float h = og * tanhf(c);
            ast(&hb[(s & 1) * 256 + jj], h);
        }
        gbar(c0, tgt);
        if (j < 256) hs[j] = ald(&hb[(s & 1) * 256 + j]);
        __syncthreads();
#pragma unroll 4
        for (int it = 0; it < 8; it++) {
            int row = it * 64 + r8i;
            const uint4* wt = (const uint4*)(WattT + (size_t)row * 256);
            float a0 = 0.f, a1 = 0.f;
#pragma unroll
            for (int i = 0; i < 4; i += 2) {
                int u0 = q + 8 * i, u1 = q + 8 * (i + 1);
                a0 += dotq(wt[u0], &hs[u0 * 8]);
                a1 += dotq(wt[u1], &hs[u1 * 8]);
            }
            float a = red8(a0 + a1);
            if (q == 0) g[row] = a;
        }
        __syncthreads();
#pragma unroll 2
        for (int it = 0; it < 2; it++) {
            int lrow = it * 64 + r8i;
            const u16* er = &encl[lrow * 520];
            float a0 = 0.f, a1 = 0.f;
#pragma unroll
            for (int i = 0; i < 8; i += 2) {
                int u0 = q + 8 * i, u1 = q + 8 * (i + 1);
                a0 += dotq(*(const uint4*)(er + u0 * 8), &g[u0 * 8]);
                a1 += dotq(*(const uint4*)(er + u1 * 8), &g[u1 * 8]);
            }
            float a = red8(a0 + a1);
            if (q == 0) evl[lrow] = expf(a);
        }
        __syncthreads();
        if (j < 64) {
            float v = evl[j] + evl[j + 64];
            for (int off = 32; off; off >>= 1) v += __shfl_down(v, off);
            if (j == 0) ast(&evsum[b * 16 + gi], v);
        }
        {
            float a0 = 0, a1 = 0, a2 = 0, a3 = 0, a4 = 0, a5 = 0, a6 = 0, a7 = 0;
#pragma unroll 4
            for (int rr = 0; rr < 16; rr++) {
                int lrow = wv * 16 + rr;
                uint4 qd = *(const uint4*)&encl[lrow * 520 + ln * 8];
                float w = evl[lrow];
                a0 += w * lo16(qd.x); a1 += w * hi16(qd.x);
                a2 += w * lo16(qd.y); a3 += w * hi16(qd.y);
                a4 += w * lo16(qd.z); a5 += w * hi16(qd.z);
                a6 += w * lo16(qd.w); a7 += w * hi16(qd.w);
            }
            float* pw = &pctxw[wv][ln * 8];
            pw[0] = a0; pw[1] = a1; pw[2] = a2; pw[3] = a3;
            pw[4] = a4; pw[5] = a5; pw[6] = a6; pw[7] = a7;
        }
        __syncthreads();
        if (j < 512) {
            float p = 0.f;
#pragma unroll
            for (int w = 0; w < 8; w++) p += pctxw[w][j];
            ast(&pctx[((size_t)b * 4 + gi) * 512 + j], p);
        }
        gbar(c0 + 16, tgt);
        if (j < 4) redw[j] = ald(&evsum[b * 16 + j]);
        if (j < 256) hc[j] = hs[j];
        __syncthreads();
        if (j < 512) {
            const float* pc = pctx + (size_t)b * 4 * 512;
            float v = ald(&pc[j]) + ald(&pc[512 + j]) + ald(&pc[1024 + j]) + ald(&pc[1536 + j]);
            hc[256 + j] = v / (redw[0] + redw[1] + redw[2] + redw[3]);
        }
        __syncthreads();
#pragma unroll 2
        for (int it = 0; it < 4; it++) {
            int row = it * 64 + r8i;
            const uint4* wc = (const uint4*)(Wcomb + (size_t)row * 768);
            float a0 = 0.f, a1 = 0.f;
#pragma unroll
            for (int i = 0; i < 12; i += 2) {
                int u0 = q + 8 * i, u1 = q + 8 * (i + 1);
                a0 += dotq(wc[u0], &hc[u0 * 8]);
                a1 += dotq(wc[u1], &hc[u1 * 8]);
            }
            float a = red8(a0 + a1);
            if (q == 0) {
                float o = tanhf(a);
                os[row] = o;
                if (gi == 0) hid[((size_t)s * 32 + b) * 256 + row] = o;
            }
        }
        __syncthreads();
    }
}

// ---------- logit at target index ----------
__global__ __launch_bounds__(256) void k_lidx(
    const int* __restrict__ target, const float* __restrict__ hid,
    const void* __restrict__ WvocV, float* __restrict__ lidx,
    const int* __restrict__ flag) {
    int p = blockIdx.x * 4 + (threadIdx.x >> 6);
    if (p >= 127 * 32) return;
    int lane = threadIdx.x & 63;
    int t = p >> 5, b = p & 31;
    int idx = target[(t + 1) * 32 + b];
    const float* h = hid + (size_t)p * 256;
    const bool f32w = (*flag != 0);
    float a = 0.f;
#pragma unroll
    for (int i = 0; i < 4; i++) {
        int k = lane * 4 + i;
        float wv = f32w ? ((const float*)WvocV)[(size_t)idx * 256 + k]
                        : b2f(((const u16*)WvocV)[(size_t)idx * 256 + k]);
        a += h[k] * wv;
    }
    for (int off = 32; off; off >>= 1) a += __shfl_down(a, off);
    if (lane == 0) lidx[p] = a;
}

// ---------- sumexp v4 (r27, MFMA, proven) ----------
__global__ __launch_bounds__(256) void k_sumexp(
    const float* __restrict__ hid, const void* __restrict__ WvocV,
    float* __restrict__ psum, const int* __restrict__ flag) {
    const int cb = blockIdx.x * 128;
    const int tid = threadIdx.x;
    const bool f32w = (*flag != 0);
    __shared__ u16 Wl[128 * 264];
    __shared__ u16 Hsb[32 * 264];
    __shared__ float red[32][2];
    for (int idx = tid; idx < 4096; idx += 256) {
        int col = idx >> 5, kc = idx & 31;
        uint4 val;
        if (f32w) {
            const float4* src = (const float4*)((const float*)WvocV + (size_t)(cb + col) * 256 + kc * 8);
            float4 f0 = src[0], f1 = src[1];
            u16 h[8];
            h[0] = f2b(f0.x); h[1] = f2b(f0.y); h[2] = f2b(f0.z); h[3] = f2b(f0.w);
            h[4] = f2b(f1.x); h[5] = f2b(f1.y); h[6] = f2b(f1.z); h[7] = f2b(f1.w);
            val = *(const uint4*)h;
        } else {
            val = *(const uint4*)((const u16*)WvocV + (size_t)(cb + col) * 256 + kc * 8);
        }
        *(uint4*)&Wl[col * 264 + kc * 8] = val;
    }
    const int wave = tid >> 6, lane = tid & 63;
    const int mtile = wave & 1;
    const int n0base = (wave >> 1) * 64;
    const int fr = lane & 15, fk = (lane >> 4) * 8;
    const int drow = mtile * 16 + (lane >> 4) * 4;
    for (int it = 0; it < 127; it++) {
        const int gr = it * 32;
        __syncthreads();
        for (int idx = tid; idx < 1024; idx += 256) {
            int row = idx >> 5, kq = idx & 31;
            const float4* hp = (const float4*)(hid + (size_t)(gr + row) * 256 + kq * 8);
            float4 f0 = hp[0], f1 = hp[1];
            u16 h[8];
            h[0] = f2b(f0.x); h[1] = f2b(f0.y); h[2] = f2b(f0.z); h[3] = f2b(f0.w);
            h[4] = f2b(f1.x); h[5] = f2b(f1.y); h[6] = f2b(f1.z); h[7] = f2b(f1.w);
            *(uint4*)&Hsb[row * 264 + kq * 8] = *(const uint4*)h;
        }
        __syncthreads();
        bf16x8 afr[8];
#pragma unroll
        for (int kc = 0; kc < 8; kc++)
            afr[kc] = *(const bf16x8*)&Hsb[(mtile * 16 + fr) * 264 + kc * 32 + fk];
        float es[4] = {0.f, 0.f, 0.f, 0.f};
#pragma unroll
        for (int nt = 0; nt < 4; nt++) {
            f32x4 acc = {0.f, 0.f, 0.f, 0.f};
            const u16* bbase = &Wl[(n0base + nt * 16 + fr) * 264 + fk];
#pragma unroll
            for (int kc = 0; kc < 8; kc++) {
                bf16x8 bfr = *(const bf16x8*)(bbase + kc * 32);
                acc = __builtin_amdgcn_mfma_f32_16x16x32_bf16(afr[kc], bfr, acc, 0, 0, 0);
            }
#pragma unroll
            for (int r = 0; r < 4; r++) es[r] += expf(acc[r]);
        }
#pragma unroll
        for (int r = 0; r < 4; r++) {
            float v = es[r];
            v += __shfl_xor(v, 1);
            v += __shfl_xor(v, 2);
            v += __shfl_xor(v, 4);
            v += __shfl_xor(v, 8);
            if ((lane & 15) == 0) red[drow + r][wave >> 1] = v;
        }
        __syncthreads();
        if (tid < 32) atomicAdd(&psum[gr + tid], red[tid][0] + red[tid][1]);
    }
}

// ---------- final scores ----------
__global__ void k_scores(const int* __restrict__ target, const float* __restrict__ lidx,
                         const float* __restrict__ psum, void* __restrict__ outv,
                         const int* __restrict__ flag) {
    int b = threadIdx.x;
    if (b >= 32) return;
    float acc = 0.f;
    for (int t = 0; t < 127; t++) {
        int idx = target[(t + 1) * 32 + b];
        if (idx != 0) {
            int row = t * 32 + b;
            acc += lidx[row] - logf(psum[row]);
        }
    }
    if (*flag) ((float*)outv)[b] = acc;
    else       ((u16*)outv)[b] = f2b(acc);
}

extern "C" void kernel_launch(void* const* d_in, const int* in_sizes, int n_in,
                              void* d_out, int out_size, void* d_ws, size_t ws_size,
                              hipStream_t stream) {
    const int* source = (const int*)d_in[0];
    const int* target = (const int*)d_in[1];
    const void* src_emb = d_in[2];
    const void* tgt_emb = d_in[3];
    const void* Wih_f = d_in[4];
    const void* Whh_f = d_in[5];
    const void* b_f = d_in[6];
    const void* Wih_b = d_in[7];
    const void* Whh_b = d_in[8];
    const void* b_b = d_in[9];
    const void* Wih_d = d_in[10];
    const void* Whh_d = d_in[11];
    const void* b_d = d_in[12];
    const void* Wh = d_in[13];
    const void* Wc = d_in[14];
    const void* Watt = d_in[15];
    const void* Wcomb = d_in[16];
    const void* Wvoc = d_in[17];

    // ---- workspace layout: [flag pad][f32 buffers][u16 buffers] ----
    int* flag = (int*)d_ws;
    float* fw = (float*)d_ws;
    size_t off = 64;
    float* hid = fw + off;    off += (size_t)127 * 32 * 256;
    float* hFB = fw + off;    off += (size_t)32 * 512;
    float* ht0 = fw + off;    off += (size_t)32 * 256;
    float* ct0 = fw + off;    off += (size_t)32 * 256;
    float* lidx = fw + off;   off += 4096;
    float* psum = fw + off;   off += 4096;
    float* hbd = fw + off;    off += (size_t)32 * 512;
    float* evsum = fw + off;  off += 512;
    float* pctx = fw + off;   off += (size_t)32 * 4 * 512;
    float* gbe = fw + off;    off += (size_t)64 * 512;
    int* cnt = (int*)(fw + off); off += 1024;
    int* cnte = (int*)(fw + off); off += 2048;
    u16* ub = (u16*)(fw + off);
    size_t uo = 0;
    u16* X = ub + uo;       uo += (size_t)512 * 32 * 256;
    u16* Yemb = ub + uo;    uo += (size_t)127 * 32 * 256;
    u16* Xf = ub + uo;      uo += (size_t)512 * 32 * 1024;
    u16* Xb = ub + uo;      uo += (size_t)512 * 32 * 1024;
    u16* Ypart = ub + uo;   uo += (size_t)127 * 32 * 1024;
    u16* enc_p = ub + uo;   uo += (size_t)32 * 512 * 512;
    u16* WattT = ub + uo;   uo += 131072;
    u16* cWih_f = ub + uo;  uo += 262144;
    u16* cWhh_f = ub + uo;  uo += 262144;
    u16* cb_f = ub + uo;    uo += 1024;
    u16* cWih_b = ub + uo;  uo += 262144;
    u16* cWhh_b = ub + uo;  uo += 262144;
    u16* cb_b = ub + uo;    uo += 1024;
    u16* cWih_d = ub + uo;  uo += 524288;
    u16* cWhh_d = ub + uo;  uo += 262144;
    u16* cb_d = ub + uo;    uo += 1024;
    u16* cWh = ub + uo;     uo += 131072;
    u16* cWc = ub + uo;     uo += 131072;
    u16* cWcomb = ub + uo;  uo += 196608;
    size_t needed = off * 4 + uo * 2;
    if (ws_size < needed) return;

    // 0. detect dtype world, canonicalize weights
    k_detect<<<1, 256, 0, stream>>>(src_emb, flag);
    auto conv = [&](const void* s, u16* d, int n) {
        k_conv<<<(n + 255) / 256, 256, 0, stream>>>(s, d, n, flag);
    };
    conv(Wih_f, cWih_f, 262144);  conv(Whh_f, cWhh_f, 262144);  conv(b_f, cb_f, 1024);
    conv(Wih_b, cWih_b, 262144);  conv(Whh_b, cWhh_b, 262144);  conv(b_b, cb_b, 1024);
    conv(Wih_d, cWih_d, 524288);  conv(Whh_d, cWhh_d, 262144);  conv(b_d, cb_d, 1024);
    conv(Wh, cWh, 131072);        conv(Wc, cWc, 131072);
    conv(Wcomb, cWcomb, 196608);
    k_wattT<<<512, 256, 0, stream>>>(Watt, WattT, flag);

    // 1. embed source
    k_embed<<<512 * 32, 256, 0, stream>>>(source, src_emb, X, flag);
    // 2. x-part gate preactivations, both directions (bf16 out)
    k_gemm_nt<u16, u16><<<dim3(16, 256), 256, 0, stream>>>(X, 256, cWih_f, 256, cb_f, Xf, 1024, 16384, 1024, 256);
    k_gemm_nt<u16, u16><<<dim3(16, 256), 256, 0, stream>>>(X, 256, cWih_b, 256, cb_b, Xb, 1024, 16384, 1024, 256);
    // 3. multi-block encoder v3
    hipMemsetAsync(cnte, 0, 2048 * sizeof(int), stream);
    k_enc_mb<<<256, 512, 0, stream>>>(Xf, Xb, cWhh_f, cWhh_b, enc_p, hFB, gbe, cnte);
    // 4. initial decoder state
    k_gemm_nt<float, float><<<dim3(4, 1), 256, 0, stream>>>(hFB, 512, cWh, 512, (const u16*)nullptr, ht0, 256, 32, 256, 512);
    k_gemm_nt<float, float><<<dim3(4, 1), 256, 0, stream>>>(hFB, 512, cWc, 512, (const u16*)nullptr, ct0, 256, 32, 256, 512);
    // 5. embed target + decoder y-part preactivations (bf16 out)
    k_embed<<<127 * 32, 256, 0, stream>>>(target, tgt_emb, Yemb, flag);
    k_gemm_nt<u16, u16><<<dim3(16, 64), 256, 0, stream>>>(Yemb, 256, cWih_d, 512, cb_d, Ypart, 1024, 4064, 1024, 256);
    // 6. multi-block decoder v6
    hipMemsetAsync(cnt, 0, 1024 * sizeof(int), stream);
    k_dec_mb<<<128, 512, 0, stream>>>(Ypart, cWhh_d, cWih_d, WattT, cWcomb, enc_p,
                                      ht0, ct0, hid, hbd, evsum, pctx, cnt);
    // 7. scores (MFMA sumexp)
    hipMemsetAsync(psum, 0, 4096 * sizeof(float), stream);
    k_lidx<<<(127 * 32 + 3) / 4, 256, 0, stream>>>(target, hid, Wvoc, lidx, flag);
    k_sumexp<<<250, 256, 0, stream>>>(hid, Wvoc, psum, flag);
    k_scores<<<1, 64, 0, stream>>>(target, lidx, psum, d_out, flag);
}